// Round 7
// baseline (334.162 us; speedup 1.0000x reference)
//
#include <hip/hip_runtime.h>
#include <math.h>

// VQ-VAE forward on MI355X (gfx950).
// z: (16,256,64,64) f32 ; emb: (1024,256) f32
// Outputs flat f32: z_q(16.7M) | loss | perp | one_hot(67.1M) | idx(65536) | d(67.1M)
//
// Round-7: prep_z and vq_zq fused into vq_mega. Mega: loads z directly (f32),
// LDS-transposes+converts to the XOR-swizzled bf16 A tile, computes znf in-block;
// K-loop (B chunks double-buffered) with in-register running top-2; epilogue writes
// d, idx, one_hot, loss partial AND z_q (emb rows staged c-major in LDS). refine
// patches idx/one_hot/hist/z_q for near-tie rows via exact-f32-chain recompute.
// Argmin semantics unchanged from validated r2-r6.

typedef unsigned short ushort;
typedef unsigned int uint;
typedef __attribute__((ext_vector_type(8))) short  bf16x8;
typedef __attribute__((ext_vector_type(8))) ushort ushort8v;
typedef __attribute__((ext_vector_type(4))) float  f32x4;

static const size_t O_LOSS = 16777216;
static const size_t O_PERP = 16777217;
static const size_t O_OH   = 16777218;   // *4B => 8 mod 16 -> float2 max
static const size_t O_IDX  = 83886082;
static const size_t O_D    = 83951618;   // float2 max

// ---- ws layout (bytes) ----
static const size_t WS_ENORM = 0;          // f32[1024]
static const size_t WS_ZNF   = 4096;       // f32[65536]
static const size_t WS_IDX   = 266240;     // i32[65536]
static const size_t WS_HIST  = 528384;     // i32[1024]
static const size_t WS_FCNT  = 532480;     // i32 (+pad)
static const size_t WS_FROWS = 532496;     // i32[65536]
static const size_t WS_LOSS  = 794640;     // f64[512] -> ends 798736
static const size_t WS_BHI   = 798736;     // bf16[1024*256] (512 KB)

#define THR_FLAG 4e-4f

__device__ __forceinline__ ushort f2bf(float f) {
  uint u = __float_as_uint(f);
  return (ushort)((u + 0x7FFFu + ((u >> 16) & 1u)) >> 16);   // RNE
}
__device__ __forceinline__ void gload16(const void* g, void* l) {
  __builtin_amdgcn_global_load_lds(
      (const __attribute__((address_space(1))) void*)g,
      (__attribute__((address_space(3))) void*)l, 16, 0, 0);
}

// ---------- prep: emb -> enormf (f64 seq, round once) + B = bf16(emb); init hist/fcnt ----------
__global__ __launch_bounds__(256) void vq_prep_e(const float* __restrict__ emb,
    float* __restrict__ enormf, ushort* __restrict__ Bhi,
    int* __restrict__ hist, int* __restrict__ flag_cnt) {
  const int j = blockIdx.x * 256 + threadIdx.x;
  hist[j] = 0;
  if (j == 0) *flag_cnt = 0;
  const float* e = emb + ((size_t)j << 8);
  ushort* br = Bhi + ((size_t)j << 8);
  double s = 0.0;
  for (int k0 = 0; k0 < 256; k0 += 8) {
    const float4 a = *(const float4*)&e[k0];
    const float4 b = *(const float4*)&e[k0 + 4];
    ushort8v v;
    v[0] = f2bf(a.x); v[1] = f2bf(a.y); v[2] = f2bf(a.z); v[3] = f2bf(a.w);
    v[4] = f2bf(b.x); v[5] = f2bf(b.y); v[6] = f2bf(b.z); v[7] = f2bf(b.w);
    *(ushort8v*)&br[k0] = v;
    s += (double)a.x * (double)a.x;  s += (double)a.y * (double)a.y;
    s += (double)a.z * (double)a.z;  s += (double)a.w * (double)a.w;
    s += (double)b.x * (double)b.x;  s += (double)b.y * (double)b.y;
    s += (double)b.z * (double)b.z;  s += (double)b.w * (double)b.w;
  }
  enormf[j] = (float)s;
}

// ---------- mega: 128 rows x 1024 codes; z->A staged in-kernel; d,idx,oh,zq,loss out ----------
__global__ __launch_bounds__(512, 4) void vq_mega(const float* __restrict__ z,
    const float* __restrict__ emb, const ushort* __restrict__ Bhi,
    const float* __restrict__ enormf, float* __restrict__ out,
    int* __restrict__ idxw, float* __restrict__ znf,
    int* __restrict__ hist, int* __restrict__ flag_cnt, int* __restrict__ flag_rows,
    double* __restrict__ loss_part) {
  __shared__ ushort As[32768];    // 64KB: bf16 A tile [128][256], k-swizzled; later f32 Et
  __shared__ ushort Bs[2][4096];  // 16KB: B chunks; prologue: f32 transpose scratch

  const int t = threadIdx.x;
  const int lane = t & 63;
  const int w = t >> 6;
  const int wr = w >> 1, wc = w & 1;
  const int g = lane >> 4, cl = lane & 15;
  const int blk = blockIdx.x;
  const int m0 = blk << 7;
  const int zb = blk >> 5;            // batch index
  const int r0 = (blk & 31) << 7;     // spatial offset within 4096
  float* dmat = out + O_D;

  // ---- A staging: z -> bf16 swizzled LDS + znorm (f64, rounded once) ----
  float* Fs = (float*)&Bs[0][0];              // [32][128] f32 chunk (16KB)
  const int kk = t >> 5, rq = t & 31;         // loader: lanes cover r (512B segs)
  const int arow = t >> 2, gq = t & 3;        // converter: 4 threads per A-row
  const int swzr = (arow & 7) << 3;
  double zn2 = 0.0;
  for (int kc = 0; kc < 256; kc += 32) {
    const float4 v0 = *(const float4*)&z[((size_t)zb << 20) + ((size_t)(kc + kk) << 12) + r0 + (rq << 2)];
    const float4 v1 = *(const float4*)&z[((size_t)zb << 20) + ((size_t)(kc + kk + 16) << 12) + r0 + (rq << 2)];
    if (kc) __syncthreads();                  // prior convert reads done
    *(float4*)&Fs[(kk << 7) + (rq << 2)] = v0;
    *(float4*)&Fs[((kk + 16) << 7) + (rq << 2)] = v1;
    __syncthreads();
    ushort8v pk;
#pragma unroll
    for (int j = 0; j < 8; ++j) {
      const float v = Fs[(((gq << 3) + j) << 7) | arow];
      zn2 += (double)v * (double)v;
      pk[j] = f2bf(v);
    }
    *(ushort8v*)&As[(arow << 8) + ((kc + (gq << 3)) ^ swzr)] = pk;
  }
  __syncthreads();
  {
    double* znp = (double*)&Bs[0][0];         // [128][4]
    znp[(arow << 2) + gq] = zn2;
  }
  __syncthreads();
  float* znf_s = (float*)((char*)&Bs[0][0] + 8192);   // in Bs[1]
  if (t < 128) {
    const double* zp = (const double*)&Bs[0][0] + (t << 2);
    const float zf = (float)(zp[0] + zp[1] + zp[2] + zp[3]);
    znf[m0 + t] = zf;                          // refine reads this
    znf_s[t] = zf;
  }
  __syncthreads();
  float zn_[2][4];
#pragma unroll
  for (int ai = 0; ai < 2; ++ai)
#pragma unroll
    for (int rg = 0; rg < 4; ++rg)
      zn_[ai][rg] = znf_s[(wr << 5) + (ai << 4) + (g << 2) + rg];
  // B chunk 0 (overwrites znp region; its reads are drained)
  gload16(Bhi + ((size_t)(t >> 2) << 8) + ((t & 3) << 3), &Bs[0][t << 3]);

  f32x4 acc[2][4];
#pragma unroll
  for (int a = 0; a < 2; ++a)
#pragma unroll
    for (int b = 0; b < 4; ++b) acc[a][b] = (f32x4)(0.0f);
  float run1[8], run2[8]; int runi[8];
#pragma unroll
  for (int r = 0; r < 8; ++r) { run1[r] = 3.0e38f; run2[r] = 3.0e38f; runi[r] = 0; }

  __syncthreads();   // zn_ reads done; B0 ready

  int cur = 0;
  for (int it = 0; it < 64; ++it) {
    const int nt = it >> 3, kch = it & 7;
    if (it < 63) {   // prefetch next B chunk
      const int nit = it + 1;
      gload16(Bhi + ((size_t)(nit >> 3) << 15) + ((nit & 7) << 5) +
                  ((size_t)(t >> 2) << 8) + ((t & 3) << 3),
              &Bs[cur ^ 1][t << 3]);
    }
    {
      const int kb = kch << 5;
      bf16x8 av[2], bv[4];
#pragma unroll
      for (int ai = 0; ai < 2; ++ai) {
        const int row = (wr << 5) + (ai << 4) + cl;
        av[ai] = *(const bf16x8*)&As[(row << 8) + ((kb + (g << 3)) ^ ((cl & 7) << 3))];
      }
#pragma unroll
      for (int bj = 0; bj < 4; ++bj)
        bv[bj] = *(const bf16x8*)&Bs[cur][(((wc << 6) + (bj << 4) + cl) << 5) + (g << 3)];
#pragma unroll
      for (int ai = 0; ai < 2; ++ai)
#pragma unroll
        for (int bj = 0; bj < 4; ++bj)
          acc[ai][bj] = __builtin_amdgcn_mfma_f32_16x16x32_bf16(av[ai], bv[bj], acc[ai][bj], 0, 0, 0);
    }
    if (kch == 7) {   // n-tile complete: emit d + fold into running top-2
      float en_[4];
#pragma unroll
      for (int bj = 0; bj < 4; ++bj)
        en_[bj] = enormf[(nt << 7) + (wc << 6) + (bj << 4) + cl];
#pragma unroll
      for (int ai = 0; ai < 2; ++ai) {
#pragma unroll
        for (int bj = 0; bj < 4; ++bj) {
          const int n = (nt << 7) + (wc << 6) + (bj << 4) + cl;
#pragma unroll
          for (int rg = 0; rg < 4; ++rg) {
            const float S = zn_[ai][rg] + en_[bj];
            const float v = S - 2.0f * acc[ai][bj][rg];
            const int m = m0 + (wr << 5) + (ai << 4) + (g << 2) + rg;
            dmat[((size_t)m << 10) + n] = v;
            const int rr = (ai << 2) + rg;
            if (v < run1[rr]) { run2[rr] = run1[rr]; run1[rr] = v; runi[rr] = n; }
            else if (v < run2[rr]) { run2[rr] = v; }
          }
          acc[ai][bj] = (f32x4)(0.0f);
        }
      }
    }
    __syncthreads();
    cur ^= 1;
  }

  // ---- epilogue scratch in Bs (all Bs reads drained by final loop barrier) ----
  float*  sd1  = (float*)&Bs[0][0];                    // [128][2]
  int*    si1  = (int*)((char*)&Bs[0][0] + 1024);
  float*  sd2  = (float*)((char*)&Bs[0][0] + 2048);
  int*    idxs = (int*)((char*)&Bs[0][0] + 3072);      // [128]
  double* red  = (double*)((char*)&Bs[0][0] + 3584);   // [128]

#pragma unroll
  for (int rr = 0; rr < 8; ++rr) {
    float a1 = run1[rr], a2 = run2[rr]; int ai1 = runi[rr];
    for (int off = 8; off >= 1; off >>= 1) {
      const float o1 = __shfl_xor(a1, off, 16);
      const int   oi = __shfl_xor(ai1, off, 16);
      const float o2 = __shfl_xor(a2, off, 16);
      const float ns = fminf(fminf(a2, o2), fmaxf(a1, o1));
      if (o1 < a1 || (o1 == a1 && oi < ai1)) { a1 = o1; ai1 = oi; }
      a2 = ns;
    }
    if (cl == 0) {
      const int r = (wr << 5) + ((rr >> 2) << 4) + (g << 2) + (rr & 3);
      sd1[(r << 1) + wc] = a1; si1[(r << 1) + wc] = ai1; sd2[(r << 1) + wc] = a2;
    }
  }
  __syncthreads();
  if (t < 128) {
    const float a1 = sd1[t << 1], b1 = sd1[(t << 1) + 1];
    const int ai1 = si1[t << 1], bi1 = si1[(t << 1) + 1];
    const float a2 = sd2[t << 1], b2 = sd2[(t << 1) + 1];
    float d1, d2; int i1;
    if (b1 < a1 || (b1 == a1 && bi1 < ai1)) { d1 = b1; i1 = bi1; d2 = fminf(a1, b2); }
    else { d1 = a1; i1 = ai1; d2 = fminf(b1, a2); }
    const int m = m0 + t;
    idxw[m] = i1; idxs[t] = i1;
    out[O_IDX + m] = (float)i1;
    atomicAdd(&hist[i1], 1);
    if (d2 - d1 < THR_FLAG) {
      const int p = atomicAdd(flag_cnt, 1);
      flag_rows[p] = m;
    }
    red[t] = (double)d1;   // loss partial (d1 = ||z-e||^2 + ~4e-4 approx; thr ~20)
  }
  __syncthreads();
  for (int off = 64; off > 0; off >>= 1) {
    if (t < off) red[t] += red[t + off];
    __syncthreads();
  }
  if (t == 0) loss_part[blk] = red[0];

  // ---- one_hot rows (zeros + single 1), 512B-coalesced ----
  float2* ohbase = (float2*)(out + O_OH);
  for (int rr = 0; rr < 16; ++rr) {
    const int r = (w << 4) + rr;
    const int idx = idxs[r];
    float2* row = ohbase + (((size_t)(m0 + r)) << 9);
    const int half = idx >> 1;
#pragma unroll
    for (int i = 0; i < 8; ++i) {
      const int slot = (i << 6) + lane;
      float2 v; v.x = 0.0f; v.y = 0.0f;
      if (slot == half) { if (idx & 1) v.y = 1.0f; else v.x = 1.0f; }
      row[slot] = v;
    }
  }

  // ---- z_q: stage selected emb rows c-major in As (pad 132), write r-coalesced ----
  float* Et = (float*)As;    // [64 c][132] f32 per chunk (33.8KB)
  for (int ch = 0; ch < 4; ++ch) {
    __syncthreads();
    {
      const int e = idxs[arow];
#pragma unroll
      for (int j2 = 0; j2 < 4; ++j2) {
        const int cb = (gq << 4) + (j2 << 2);
        const float4 ev = *(const float4*)&emb[((size_t)e << 8) + (ch << 6) + cb];
        Et[(cb + 0) * 132 + arow] = ev.x;
        Et[(cb + 1) * 132 + arow] = ev.y;
        Et[(cb + 2) * 132 + arow] = ev.z;
        Et[(cb + 3) * 132 + arow] = ev.w;
      }
    }
    __syncthreads();
#pragma unroll
    for (int i = 0; i < 8; ++i) {
      const int cll = (w << 3) + i;
      const int c = (ch << 6) + cll;
#pragma unroll
      for (int h = 0; h < 2; ++h) {
        const int rr = (h << 6) + lane;
        out[((size_t)zb << 20) + ((size_t)c << 12) + r0 + rr] = Et[cll * 132 + rr];
      }
    }
  }
}

// ---------- candidate-based exact f32-chain refine + patch idx/one_hot/hist/z_q ----------
__global__ __launch_bounds__(256) void vq_refine(const float* __restrict__ z,
    const float* __restrict__ emb, const float* __restrict__ znf,
    const float* __restrict__ enormf, const int* __restrict__ flag_cnt,
    const int* __restrict__ flag_rows, int* __restrict__ idxw,
    float* __restrict__ out, int* __restrict__ hist) {
  __shared__ float zrow[256];
  __shared__ float dmin_s[4];
  __shared__ int cand[256];
  __shared__ int ncand_s;
  __shared__ int old_s;
  __shared__ float rv[256];
  __shared__ int ri[256];
  const float* dmat = out + O_D;
  const int t = threadIdx.x;
  const int n = *flag_cnt;
  for (int f = blockIdx.x; f < n; f += gridDim.x) {
    const int m = flag_rows[f];
    __syncthreads();
    if (t == 0) { ncand_s = 0; old_s = idxw[m]; }
    zrow[t] = z[(((size_t)(m >> 12)) << 20) + (size_t)(m & 4095) + ((size_t)t << 12)];
    const float* dr = dmat + ((size_t)m << 10);
    const float2 a = *(const float2*)&dr[t << 2];
    const float2 b = *(const float2*)&dr[(t << 2) + 2];
    float dmin = fminf(fminf(a.x, a.y), fminf(b.x, b.y));
    for (int off = 32; off >= 1; off >>= 1) dmin = fminf(dmin, __shfl_xor(dmin, off));
    if ((t & 63) == 0) dmin_s[t >> 6] = dmin;
    __syncthreads();
    dmin = fminf(fminf(dmin_s[0], dmin_s[1]), fminf(dmin_s[2], dmin_s[3]));
    const float lim = dmin + THR_FLAG;
    const float dv[4] = {a.x, a.y, b.x, b.y};
#pragma unroll
    for (int q = 0; q < 4; ++q)
      if (dv[q] <= lim) {
        const int p = atomicAdd(&ncand_s, 1);
        if (p < 256) cand[p] = (t << 2) + q;
      }
    __syncthreads();
    const int nc = min(ncand_s, 256);
    float best = 3.0e38f; int bi = 1 << 30;
    if (t < nc) {
      const int j = cand[t];
      const float* er = emb + ((size_t)j << 8);
      float s = 0.0f;
      for (int k = 0; k < 256; ++k) s = fmaf(zrow[k], er[k], s);
      const float S = znf[m] + enormf[j];
      best = S - 2.0f * s;
      bi = j;
    }
    rv[t] = best; ri[t] = bi;
    __syncthreads();
    for (int off = 128; off > 0; off >>= 1) {
      if (t < off) {
        const float ov = rv[t + off]; const int oi = ri[t + off];
        if (ov < rv[t] || (ov == rv[t] && oi < ri[t])) { rv[t] = ov; ri[t] = oi; }
      }
      __syncthreads();
    }
    const int nbi = ri[0];
    const int old = old_s;
    if (nbi != old) {
      if (t == 0) {
        idxw[m] = nbi;
        out[O_IDX + m] = (float)nbi;
        out[O_OH + ((size_t)m << 10) + (size_t)old] = 0.0f;
        out[O_OH + ((size_t)m << 10) + (size_t)nbi] = 1.0f;
        atomicAdd(&hist[old], -1);
        atomicAdd(&hist[nbi], 1);
      }
      // patch z_q row (z layout: b<<20 | c<<12 | r)
      out[(((size_t)(m >> 12)) << 20) + ((size_t)t << 12) + (size_t)(m & 4095)] =
          emb[((size_t)nbi << 8) + t];
    }
  }
}

__global__ __launch_bounds__(256) void vq_final(const double* __restrict__ loss_part,
    const int* __restrict__ hist, float* __restrict__ out) {
  __shared__ double red[256];
  const int t = threadIdx.x;
  red[t] = loss_part[t] + loss_part[t + 256];
  __syncthreads();
  for (int off = 128; off > 0; off >>= 1) {
    if (t < off) red[t] += red[t + off];
    __syncthreads();
  }
  if (t == 0) out[O_LOSS] = (float)(1.25 * red[0] / 16777216.0);
  __syncthreads();
  double h = 0.0;
  for (int i = t; i < 1024; i += 256) {
    const double p = (double)hist[i] / 65536.0;
    h += p * log(p + 1e-10);
  }
  red[t] = h;
  __syncthreads();
  for (int off = 128; off > 0; off >>= 1) {
    if (t < off) red[t] += red[t + off];
    __syncthreads();
  }
  if (t == 0) out[O_PERP] = (float)exp(-red[0]);
}

extern "C" void kernel_launch(void* const* d_in, const int* in_sizes, int n_in,
                              void* d_out, int out_size, void* d_ws, size_t ws_size,
                              hipStream_t stream) {
  const float* z   = (const float*)d_in[0];
  const float* emb = (const float*)d_in[1];
  float* out = (float*)d_out;
  char* ws = (char*)d_ws;

  float*  enormf    = (float*)(ws + WS_ENORM);
  float*  znf       = (float*)(ws + WS_ZNF);
  int*    idxw      = (int*)(ws + WS_IDX);
  int*    hist      = (int*)(ws + WS_HIST);
  int*    flag_cnt  = (int*)(ws + WS_FCNT);
  int*    flag_rows = (int*)(ws + WS_FROWS);
  double* loss_part = (double*)(ws + WS_LOSS);
  ushort* Bhi       = (ushort*)(ws + WS_BHI);

  vq_prep_e<<<4, 256, 0, stream>>>(emb, enormf, Bhi, hist, flag_cnt);
  vq_mega<<<512, 512, 0, stream>>>(z, emb, Bhi, enormf, out, idxw, znf, hist,
                                   flag_cnt, flag_rows, loss_part);
  vq_refine<<<4096, 256, 0, stream>>>(z, emb, znf, enormf, flag_cnt, flag_rows,
                                      idxw, out, hist);
  vq_final<<<1, 256, 0, stream>>>(loss_part, hist, out);
}